// Round 4
// baseline (299.368 us; speedup 1.0000x reference)
//
#include <hip/hip_runtime.h>
#include <math.h>

// Problem constants
#define DD    2048   // model dim
#define EE    64     // num experts
#define NTOK  8192   // B*T

// Output layout (all read back as float32 by harness):
//   router_probs [4,2048,64]  -> 524288 floats @ 0
//   top_k_indices [4,2048,2]  -> 16384 floats  @ 524288
//   exp_mask [2, 8192, 64]    -> 1048576 floats @ 540672
#define PROB_OFF 0
#define IDX_OFF  524288
#define MASK_OFF 540672
#define MASK_K_STRIDE (NTOK * EE)   // 524288

typedef float v2f __attribute__((ext_vector_type(2)));

// ---------------------------------------------------------------------------
// GEMM, single-wave blocks (x addresses provably uniform -> s_load / SGPRs).
// lanes 0..31 = gate, 32..63 = noise; each lane owns 2 adjacent expert
// columns as a v2f -> one v_pk_fma_f32 per (token, k) covers all 128 output
// columns. Two-phase software pipeline: w (VGPR v2f) and x (SGPR) are
// double-buffered one KSTEP ahead; loop body written twice so every local
// array index is compile-time constant (registers, never scratch).
// Partials: [NTOK][KSPLIT][2*EE], contiguous per token for the epilogue.
// ---------------------------------------------------------------------------
template <int KSPLIT, int TT, int KSTEP>
__global__ __launch_bounds__(64) void router_gemm(
    const float* __restrict__ x,        // [NTOK][DD]
    const float* __restrict__ w_gate,   // [DD][EE]
    const float* __restrict__ w_noise,  // [DD][EE]
    float* __restrict__ part)           // [NTOK][KSPLIT][2*EE]
{
  constexpr int KR = DD / KSPLIT;

  const int lane = threadIdx.x;        // 0..63
  const int tok0 = blockIdx.x * TT;    // uniform
  const int ks   = blockIdx.y;         // uniform
  const int k0   = ks * KR;            // uniform
  const int le   = lane & 31;

  const float* __restrict__ W =
      ((lane & 32) ? w_noise : w_gate) + 2 * le + (size_t)k0 * EE;
  const float* __restrict__ xb = x + (size_t)tok0 * DD + k0;  // uniform base

  v2f acc[TT];
#pragma unroll
  for (int t = 0; t < TT; ++t) acc[t] = v2f{0.0f, 0.0f};

  v2f   wv[2][KSTEP];       // VGPR double buffer (per-lane w columns)
  float xs[2][TT][KSTEP];   // SGPR double buffer (uniform x scalars)

  // prologue: fill phase-0 buffers at k = 0
#pragma unroll
  for (int u = 0; u < KSTEP; ++u)
    wv[0][u] = *reinterpret_cast<const v2f*>(W + (size_t)u * EE);
#pragma unroll
  for (int t = 0; t < TT; ++t)
#pragma unroll
    for (int u = 0; u < KSTEP; ++u)
      xs[0][t][u] = xb[(size_t)t * DD + u];

  for (int k = 0; k < KR; k += 2 * KSTEP) {
    // prefetch phase-1 buffers at k + KSTEP (always in range)
#pragma unroll
    for (int u = 0; u < KSTEP; ++u)
      wv[1][u] = *reinterpret_cast<const v2f*>(W + (size_t)(k + KSTEP + u) * EE);
#pragma unroll
    for (int t = 0; t < TT; ++t)
#pragma unroll
      for (int u = 0; u < KSTEP; ++u)
        xs[1][t][u] = xb[(size_t)t * DD + (k + KSTEP + u)];

    // compute phase 0
#pragma unroll
    for (int t = 0; t < TT; ++t)
#pragma unroll
      for (int u = 0; u < KSTEP; ++u) {
        const v2f xsp = {xs[0][t][u], xs[0][t][u]};
        acc[t] = __builtin_elementwise_fma(xsp, wv[0][u], acc[t]);
      }

    // prefetch phase-0 buffers at k + 2*KSTEP (guarded; uniform branch)
    if (k + 2 * KSTEP < KR) {
#pragma unroll
      for (int u = 0; u < KSTEP; ++u)
        wv[0][u] = *reinterpret_cast<const v2f*>(W + (size_t)(k + 2 * KSTEP + u) * EE);
#pragma unroll
      for (int t = 0; t < TT; ++t)
#pragma unroll
        for (int u = 0; u < KSTEP; ++u)
          xs[0][t][u] = xb[(size_t)t * DD + (k + 2 * KSTEP + u)];
    }

    // compute phase 1
#pragma unroll
    for (int t = 0; t < TT; ++t)
#pragma unroll
      for (int u = 0; u < KSTEP; ++u) {
        const v2f xsp = {xs[1][t][u], xs[1][t][u]};
        acc[t] = __builtin_elementwise_fma(xsp, wv[1][u], acc[t]);
      }
  }

  // store: token-major partials, gate cols at words 0..63, noise at 64..127
  float* o = part + ((size_t)tok0 * KSPLIT + ks) * (2 * EE) +
             ((lane & 32) ? EE : 0) + 2 * le;
#pragma unroll
  for (int t = 0; t < TT; ++t)
    *reinterpret_cast<v2f*>(o + (size_t)t * KSPLIT * (2 * EE)) = acc[t];
}

// ---------------------------------------------------------------------------
// Epilogue: one wave per token. Sum ksplit partials (contiguous 2KB/token),
// softplus-noise, top-2 (jax tie semantics: desc value, asc index), softmax
// over 2, scatter probs + indices + one-hot masks.
// ---------------------------------------------------------------------------
__global__ __launch_bounds__(256) void router_epilogue(
    const float* __restrict__ part,      // [NTOK][ksplit][2*EE]
    const float* __restrict__ noise_eps, // [NTOK][EE]
    float* __restrict__ out, int ksplit)
{
  const int t    = blockIdx.x * 4 + (threadIdx.x >> 6);
  const int lane = threadIdx.x & 63;

  const float* p = part + (size_t)t * ksplit * (2 * EE);
  float g = 0.0f, nraw = 0.0f;
  for (int s = 0; s < ksplit; ++s) {
    g    += p[s * (2 * EE) + lane];
    nraw += p[s * (2 * EE) + EE + lane];
  }
  const float ep = noise_eps[(size_t)t * EE + lane];

  // softplus(nraw) = max(nraw,0) + log1p(exp(-|nraw|))
  const float sp = fmaxf(nraw, 0.0f) + log1pf(expf(-fabsf(nraw)));
  const float z  = fmaf(sp, ep, g);

  // top-1 butterfly (all lanes converge)
  float v1 = z; int i1 = lane;
#pragma unroll
  for (int off = 32; off >= 1; off >>= 1) {
    const float ov = __shfl_xor(v1, off, 64);
    const int   oi = __shfl_xor(i1, off, 64);
    if (ov > v1 || (ov == v1 && oi < i1)) { v1 = ov; i1 = oi; }
  }
  // top-2: exclude winner
  float v2 = (lane == i1) ? -INFINITY : z; int i2 = lane;
#pragma unroll
  for (int off = 32; off >= 1; off >>= 1) {
    const float ov = __shfl_xor(v2, off, 64);
    const int   oi = __shfl_xor(i2, off, 64);
    if (ov > v2 || (ov == v2 && oi < i2)) { v2 = ov; i2 = oi; }
  }

  const float e2 = expf(v2 - v1);
  const float denom = 1.0f + e2;
  const float p1 = 1.0f / denom;
  const float p2 = e2 / denom;

  out[PROB_OFF + (size_t)t * EE + lane] =
      (lane == i1) ? p1 : ((lane == i2) ? p2 : 0.0f);

  if (lane == 0) {
    out[IDX_OFF + t * 2 + 0] = (float)i1;
    out[IDX_OFF + t * 2 + 1] = (float)i2;
  }

  out[MASK_OFF + 0 * MASK_K_STRIDE + (size_t)t * EE + lane] = (lane == i1) ? 1.0f : 0.0f;
  out[MASK_OFF + 1 * MASK_K_STRIDE + (size_t)t * EE + lane] = (lane == i2) ? 1.0f : 0.0f;
}

// ---------------------------------------------------------------------------
extern "C" void kernel_launch(void* const* d_in, const int* in_sizes, int n_in,
                              void* d_out, int out_size, void* d_ws, size_t ws_size,
                              hipStream_t stream) {
  const float* x   = (const float*)d_in[0];
  const float* eps = (const float*)d_in[1];
  const float* wg  = (const float*)d_in[2];
  const float* wn  = (const float*)d_in[3];
  float* out = (float*)d_out;
  float* ws  = (float*)d_ws;

  const size_t part_bytes = (size_t)NTOK * 2 * EE * sizeof(float);  // 4 MB/split

  int ksplit;
  if (ws_size >= 4 * part_bytes)      ksplit = 4;   // 16 MB (known to fit)
  else if (ws_size >= 2 * part_bytes) ksplit = 2;
  else                                ksplit = 1;

  if (ksplit == 4) {
    router_gemm<4, 16, 2><<<dim3(NTOK / 16, 4), dim3(64), 0, stream>>>(x, wg, wn, ws);
  } else if (ksplit == 2) {
    router_gemm<2, 16, 2><<<dim3(NTOK / 16, 2), dim3(64), 0, stream>>>(x, wg, wn, ws);
  } else {
    router_gemm<1, 16, 2><<<dim3(NTOK / 16, 1), dim3(64), 0, stream>>>(x, wg, wn, ws);
  }

  router_epilogue<<<dim3(NTOK / 4), dim3(256), 0, stream>>>(ws, eps, out, ksplit);
}